// Round 1
// baseline (1535.850 us; speedup 1.0000x reference)
//
#include <hip/hip_runtime.h>
#include <math.h>

#define B 4
#define C 448
#define P 3136     // 56*56
#define N 200
#define K_IM 50
#define C4 112     // C/4 (float4 count per row)

// workspace layout (float offsets)
#define WS_ET    0                         // B*P*C      = 5,619,712
#define WS_PE2   (WS_ET + B*P*C)           // B*P        = 12,544
#define WS_PCR   (WS_PE2 + B*P)            // B*N*P      = 2,508,800
#define WS_PM2   (WS_PCR + B*N*P)          // N*P        = 627,200
#define WS_CROSS (WS_PM2 + N*P)            // B*N        = 800
#define WS_M2    (WS_CROSS + B*N)          // N          = 200
#define WS_TOPK  (WS_M2 + N)               // B*K_IM ints
// total ~8.77M floats ~= 35.1 MB

// ---------- kernel 1: [B,C,H,W] -> [B,P,C] tiled transpose ----------
__global__ __launch_bounds__(256) void transpose_kernel(
        const float* __restrict__ emb, float* __restrict__ eT) {
    __shared__ float tile[64][65];
    int b  = blockIdx.z;
    int c0 = blockIdx.y * 64;
    int p0 = blockIdx.x * 64;
    int tx = threadIdx.x;  // 0..63
    int ty = threadIdx.y;  // 0..3
    const float* src = emb + ((size_t)b * C + c0) * P + p0;
#pragma unroll
    for (int i = 0; i < 16; ++i) {
        int row = ty + 4 * i;               // c within tile
        tile[row][tx] = src[(size_t)row * P + tx];
    }
    __syncthreads();
    float* dst = eT + ((size_t)b * P + p0) * C + c0;
#pragma unroll
    for (int i = 0; i < 16; ++i) {
        int prow = ty + 4 * i;              // p within tile
        dst[(size_t)prow * C + tx] = tile[tx][prow];
    }
}

// ---------- kernel 2: main fused pass over memory_bank ----------
// grid = P blocks; block = 256 (4 waves). Wave w handles images n = 4i+w.
__global__ __launch_bounds__(256) void main_kernel(
        const float* __restrict__ eT, const float* __restrict__ M,
        float* __restrict__ pe2, float* __restrict__ pcross,
        float* __restrict__ pm2) {
    __shared__ float4 eL[B][C4];
    int p = blockIdx.x;
    int t = threadIdx.x;
    int w = t >> 6;
    int l = t & 63;

    // stage e[b][p][:] for all 4 b into LDS (448 float4 total)
    for (int idx = t; idx < B * C4; idx += 256) {
        int bb = idx / C4, r = idx - bb * C4;
        eL[bb][r] = reinterpret_cast<const float4*>(eT + ((size_t)bb * P + p) * C)[r];
    }
    __syncthreads();

    // pe2[b][p]: wave w computes b = w
    {
        float s = 0.f;
        for (int j = l; j < C4; j += 64) {
            float4 v = eL[w][j];
            s += v.x * v.x + v.y * v.y + v.z * v.z + v.w * v.w;
        }
#pragma unroll
        for (int off = 32; off >= 1; off >>= 1) s += __shfl_xor(s, off);
        if (l == 0) pe2[(size_t)w * P + p] = s;
    }

    for (int i = 0; i < N / 4; ++i) {
        int n = i * 4 + w;
        const float4* Mp = reinterpret_cast<const float4*>(M + ((size_t)n * P + p) * C);
        float d0 = 0.f, d1 = 0.f, d2 = 0.f, d3 = 0.f, s = 0.f;
#pragma unroll
        for (int jj = 0; jj < 2; ++jj) {
            int j = l + 64 * jj;
            if (j < C4) {
                float4 m  = Mp[j];
                float4 e0 = eL[0][j], e1 = eL[1][j], e2v = eL[2][j], e3 = eL[3][j];
                d0 += m.x * e0.x + m.y * e0.y + m.z * e0.z + m.w * e0.w;
                d1 += m.x * e1.x + m.y * e1.y + m.z * e1.z + m.w * e1.w;
                d2 += m.x * e2v.x + m.y * e2v.y + m.z * e2v.z + m.w * e2v.w;
                d3 += m.x * e3.x + m.y * e3.y + m.z * e3.z + m.w * e3.w;
                s  += m.x * m.x + m.y * m.y + m.z * m.z + m.w * m.w;
            }
        }
#pragma unroll
        for (int off = 32; off >= 1; off >>= 1) {
            d0 += __shfl_xor(d0, off);
            d1 += __shfl_xor(d1, off);
            d2 += __shfl_xor(d2, off);
            d3 += __shfl_xor(d3, off);
            s  += __shfl_xor(s, off);
        }
        if (l == 0) {
            pcross[((size_t)0 * N + n) * P + p] = d0;
            pcross[((size_t)1 * N + n) * P + p] = d1;
            pcross[((size_t)2 * N + n) * P + p] = d2;
            pcross[((size_t)3 * N + n) * P + p] = d3;
            pm2[(size_t)n * P + p] = s;
        }
    }
}

// ---------- kernel 3: reduce pcross/pm2 over p -> cross[b][n], m2[n] ----------
__global__ __launch_bounds__(256) void reduce_kernel(
        const float* __restrict__ pcross, const float* __restrict__ pm2,
        float* __restrict__ cross, float* __restrict__ m2) {
    int bid = blockIdx.x;
    const float* src = (bid < B * N) ? (pcross + (size_t)bid * P)
                                     : (pm2 + (size_t)(bid - B * N) * P);
    int t = threadIdx.x;
    float s = 0.f;
    const float4* s4 = reinterpret_cast<const float4*>(src);
    for (int j = t; j < P / 4; j += 256) {  // 784 float4
        float4 v = s4[j];
        s += v.x + v.y + v.z + v.w;
    }
    __shared__ float wsum[4];
#pragma unroll
    for (int off = 32; off >= 1; off >>= 1) s += __shfl_xor(s, off);
    if ((t & 63) == 0) wsum[t >> 6] = s;
    __syncthreads();
    if (t == 0) {
        float tot = wsum[0] + wsum[1] + wsum[2] + wsum[3];
        if (bid < B * N) cross[bid] = tot;
        else m2[bid - B * N] = tot;
    }
}

// ---------- kernel 4: image distances + top-50 selection + pred_scores ----------
__global__ __launch_bounds__(256) void final_kernel(
        const float* __restrict__ pe2, const float* __restrict__ cross,
        const float* __restrict__ m2, float* __restrict__ out,
        int* __restrict__ topk) {
    __shared__ float e2s[B];
    __shared__ float sdist[B * N];
    int t = threadIdx.x, w = t >> 6, l = t & 63;
    // e2[b] = sum_p pe2[b][p]; wave w handles b=w
    float s = 0.f;
    for (int j = l; j < P; j += 64) s += pe2[(size_t)w * P + j];
#pragma unroll
    for (int off = 32; off >= 1; off >>= 1) s += __shfl_xor(s, off);
    if (l == 0) e2s[w] = s;
    __syncthreads();
    for (int r = t; r < B * N; r += 256) {
        int b = r / N, n = r - b * N;
        sdist[r] = sqrtf(fmaxf(e2s[b] + m2[n] - 2.f * cross[r], 0.f));
    }
    __syncthreads();
    // wave w selects 50 smallest for b=w (lane l owns n = l, l+64, l+128, l+192)
    float vals[4];
#pragma unroll
    for (int sl = 0; sl < 4; ++sl) {
        int n = l + 64 * sl;
        vals[sl] = (n < N) ? sdist[w * N + n] : INFINITY;
    }
    float sum = 0.f;
    for (int k = 0; k < K_IM; ++k) {
        float v = INFINITY;
        int idx = N;
#pragma unroll
        for (int sl = 0; sl < 4; ++sl) {
            int n = l + 64 * sl;
            if (vals[sl] < v || (vals[sl] == v && n < idx)) { v = vals[sl]; idx = n; }
        }
#pragma unroll
        for (int off = 32; off >= 1; off >>= 1) {
            float ov = __shfl_xor(v, off);
            int oi = __shfl_xor(idx, off);
            if (ov < v || (ov == v && oi < idx)) { v = ov; idx = oi; }
        }
        sum += v;
        if ((idx & 63) == l) vals[idx >> 6] = INFINITY;  // remove winner
        if (l == 0) topk[w * K_IM + k] = idx;
    }
    if (l == 0) out[w] = sum * (1.f / K_IM);
}

// ---------- kernel 5: per-patch min over the 50 selected images ----------
__global__ __launch_bounds__(256) void patch_kernel(
        const float* __restrict__ pe2, const float* __restrict__ pm2,
        const float* __restrict__ pcross, const int* __restrict__ topk,
        float* __restrict__ out) {
    __shared__ int kl[K_IM];
    int b = blockIdx.y;
    int t = threadIdx.x;
    if (t < K_IM) kl[t] = topk[b * K_IM + t];
    __syncthreads();
    int p = blockIdx.x * 256 + t;
    if (p >= P) return;
    float pe = pe2[(size_t)b * P + p];
    float best = INFINITY;
    for (int k = 0; k < K_IM; ++k) {
        int n = kl[k];
        float d = pe + pm2[(size_t)n * P + p] - 2.f * pcross[((size_t)b * N + n) * P + p];
        best = fminf(best, sqrtf(fmaxf(d, 0.f)));
    }
    out[4 + (size_t)b * P + p] = best;
}

extern "C" void kernel_launch(void* const* d_in, const int* in_sizes, int n_in,
                              void* d_out, int out_size, void* d_ws, size_t ws_size,
                              hipStream_t stream) {
    const float* emb = (const float*)d_in[0];   // [4,448,56,56]
    const float* M   = (const float*)d_in[1];   // [200,3136,448]
    float* out = (float*)d_out;                 // [4] pred + [4*3136] patch
    float* ws  = (float*)d_ws;

    float* eT     = ws + WS_ET;
    float* pe2    = ws + WS_PE2;
    float* pcross = ws + WS_PCR;
    float* pm2    = ws + WS_PM2;
    float* cross  = ws + WS_CROSS;
    float* m2     = ws + WS_M2;
    int*   topk   = (int*)(ws + WS_TOPK);

    transpose_kernel<<<dim3(P / 64, C / 64, B), dim3(64, 4), 0, stream>>>(emb, eT);
    main_kernel<<<P, 256, 0, stream>>>(eT, M, pe2, pcross, pm2);
    reduce_kernel<<<B * N + N, 256, 0, stream>>>(pcross, pm2, cross, m2);
    final_kernel<<<1, 256, 0, stream>>>(pe2, cross, m2, out, topk);
    patch_kernel<<<dim3((P + 255) / 256, B), 256, 0, stream>>>(pe2, pm2, pcross, topk, out);
}